// Round 14
// baseline (215.834 us; speedup 1.0000x reference)
//
#include <hip/hip_runtime.h>

#define B_   2
#define N_   512
#define DM_  1024
#define H_   16
#define LAM_ 0.1f

typedef __attribute__((ext_vector_type(8))) short bf16x8;
typedef __attribute__((ext_vector_type(4))) float f32x4;
typedef unsigned short ush;
struct ush4 { ush x, y, z, w; };
struct uint2s { unsigned x, y; };

__device__ inline ush f2bf(float v) {
    union { float f; unsigned u; } c; c.f = v;
    unsigned r = c.u + 0x7FFF + ((c.u >> 16) & 1);
    return (ush)(r >> 16);
}
__device__ inline float bf2f(ush b) {
    union { float f; unsigned u; } c; c.u = ((unsigned)b) << 16; return c.f;
}
__device__ inline f32x4 mfma16(bf16x8 a, bf16x8 b, f32x4 c) {
    return __builtin_amdgcn_mfma_f32_16x16x32_bf16(a, b, c, 0, 0, 0);
}
// jnp.argmax semantics (first max wins); uniform -> scalar loads
__device__ inline int sel_of(const float* __restrict__ lg) {
    float b = lg[0]; int s = 0;
    if (lg[1] > b) { b = lg[1]; s = 1; }
    if (lg[2] > b) { b = lg[2]; s = 2; }
    if (lg[3] > b) { b = lg[3]; s = 3; }
    return s;
}

// V^T padded stride per head: data rows [0,hd), ones row at hd, zeros to PT
template<int HD> struct vpad_t { static constexpr int PT = (HD >= 16) ? HD + 16 : 16; };

// ---------------------------------------------------------------------------
// fused prep. Region map (256-thread blocks):
//   [0,    1024): x+pe -> bf16 hi/lo, float4-vectorized
//   [1024, 1792): wqkv transpose, 64x64 LDS tiles
//   [1792, 2048): wo transpose, 64x64 LDS tiles
//   [2048, 3072): V^T pad fill (ones row at hd, zeros above)
// ---------------------------------------------------------------------------
template<int D>
__device__ void prep_wt_tile(int bT, int tid, const float* __restrict__ w,
                             ush* __restrict__ wh, ush* __restrict__ wl,
                             float (*lds)[65]) {
    constexpr int ds = DM_ / D;
    constexpr int tpr = 3 * ds / 64;
    constexpr int tpc = ds / 64;
    constexpr int tpd = tpr * tpc;
    if (bT >= D * tpd) return;
    const int d = bT / tpd, rem = bT % tpd;
    const int tr = rem / tpr, tc = rem % tpr;
    const float* src = w + (size_t)d * ds * 3 * ds;
    ush* dsth = wh + (size_t)d * 3 * ds * ds;
    ush* dstl = wl + (size_t)d * 3 * ds * ds;
    const int c = tid & 63, r0 = tid >> 6;
    #pragma unroll
    for (int j = 0; j < 16; ++j) {
        const int r = j * 4 + r0;
        lds[r][c] = src[(size_t)(tr * 64 + r) * (3 * ds) + tc * 64 + c];
    }
    __syncthreads();
    #pragma unroll
    for (int j = 0; j < 16; ++j) {
        const int r = j * 4 + r0;
        const float v = lds[c][r];
        const size_t o = (size_t)(tc * 64 + r) * ds + tr * 64 + c;
        const ush h = f2bf(v);
        dsth[o] = h; dstl[o] = f2bf(v - bf2f(h));
    }
}
template<int D>
__device__ void prep_vpad(int bT, int tid, ush* __restrict__ Vth, ush* __restrict__ Vtl) {
    constexpr int ds = DM_ / D, hd = ds / H_;
    constexpr int PT = vpad_t<hd>::PT;
    constexpr int NH = B_ * D * H_;
    constexpr int PR = PT - hd;
    constexpr int TOT = NH * PR * (N_ / 4);
    const int g = bT * 256 + tid;
    if (g >= TOT) return;
    constexpr int perh = PR * (N_ / 4);
    const int head = g / perh, rem = g % perh;
    const int r = hd + rem / (N_ / 4), n4 = (rem % (N_ / 4)) * 4;
    const size_t o = ((size_t)head * PT + r) * N_ + n4;
    const ush one = (r == hd) ? (ush)0x3F80 : (ush)0;
    ush4 hv; hv.x = one; hv.y = one; hv.z = one; hv.w = one;
    ush4 zv; zv.x = 0; zv.y = 0; zv.z = 0; zv.w = 0;
    *(ush4*)&Vth[o] = hv;
    *(ush4*)&Vtl[o] = zv;
}
__global__ __launch_bounds__(256) void k_prep(
        const float* __restrict__ logits, const float* __restrict__ x,
        const float* __restrict__ pe0, const float* __restrict__ pe1,
        const float* __restrict__ pe2, const float* __restrict__ pe3,
        const float* __restrict__ w0, const float* __restrict__ w1,
        const float* __restrict__ w2, const float* __restrict__ w3,
        const float* __restrict__ wo0, const float* __restrict__ wo1,
        const float* __restrict__ wo2, const float* __restrict__ wo3,
        ush* __restrict__ xh, ush* __restrict__ xl,
        ush* __restrict__ wqh, ush* __restrict__ wql,
        ush* __restrict__ woh, ush* __restrict__ wol,
        ush* __restrict__ Vth, ush* __restrict__ Vtl) {
    __shared__ float lds[64][65];
    const int s = sel_of(logits);
    const int bid = blockIdx.x, tid = threadIdx.x;
    if (bid < 1024) {
        const float* pe = (s == 0) ? pe0 : (s == 1) ? pe1 : (s == 2) ? pe2 : pe3;
        const size_t i0 = ((size_t)bid * 256 + tid) * 4;
        const float4 xv = *(const float4*)&x[i0];
        const float4 pv = *(const float4*)&pe[i0 & ((size_t)N_ * DM_ - 1)];
        ush4 h4, l4;
        float v;
        v = xv.x + pv.x; h4.x = f2bf(v); l4.x = f2bf(v - bf2f(h4.x));
        v = xv.y + pv.y; h4.y = f2bf(v); l4.y = f2bf(v - bf2f(h4.y));
        v = xv.z + pv.z; h4.z = f2bf(v); l4.z = f2bf(v - bf2f(h4.z));
        v = xv.w + pv.w; h4.w = f2bf(v); l4.w = f2bf(v - bf2f(h4.w));
        *(ush4*)&xh[i0] = h4;
        *(ush4*)&xl[i0] = l4;
    } else if (bid < 1792) {
        const int bT = bid - 1024;
        switch (s) {
            case 0: prep_wt_tile<1>(bT, tid, w0, wqh, wql, lds); break;
            case 1: prep_wt_tile<2>(bT, tid, w1, wqh, wql, lds); break;
            case 2: prep_wt_tile<4>(bT, tid, w2, wqh, wql, lds); break;
            case 3: prep_wt_tile<8>(bT, tid, w3, wqh, wql, lds); break;
        }
    } else if (bid < 2048) {
        const float* w = (s == 0) ? wo0 : (s == 1) ? wo1 : (s == 2) ? wo2 : wo3;
        const int bT = bid - 1792;
        const int tr = bT >> 4, tc = bT & 15;
        const int c = tid & 63, r0 = tid >> 6;
        #pragma unroll
        for (int j = 0; j < 16; ++j) {
            const int r = j * 4 + r0;
            lds[r][c] = w[(size_t)(tr * 64 + r) * DM_ + tc * 64 + c];
        }
        __syncthreads();
        #pragma unroll
        for (int j = 0; j < 16; ++j) {
            const int r = j * 4 + r0;
            const float v = lds[c][r];
            const size_t o = (size_t)(tc * 64 + r) * DM_ + tr * 64 + c;
            const ush h = f2bf(v);
            woh[o] = h; wol[o] = f2bf(v - bf2f(h));
        }
    } else {
        const int bT = bid - 2048;
        switch (s) {
            case 0: prep_vpad<1>(bT, tid, Vth, Vtl); break;
            case 1: prep_vpad<2>(bT, tid, Vth, Vtl); break;
            case 2: prep_vpad<4>(bT, tid, Vth, Vtl); break;
            case 3: prep_vpad<8>(bT, tid, Vth, Vtl); break;
        }
    }
}

// ---------------------------------------------------------------------------
// Split-bf16 MFMA GEMM core (64x64 tile, BK=32, 4 waves) — used by k_qkv
// ---------------------------------------------------------------------------
template<int KD>
__device__ void gemm_core(const ush* __restrict__ Ah, const ush* __restrict__ Al, int lda,
                          const ush* __restrict__ Bh, const ush* __restrict__ Bl, int ldb,
                          int row0, int col0, int tid, ush* lds, f32x4 acc[2][2]) {
    ush* lAh = lds; ush* lAl = lds + 2560; ush* lBh = lds + 5120; ush* lBl = lds + 7680;
    const int srow = tid >> 2, scg = tid & 3;
    const int lane = tid & 63, w = tid >> 6;
    const int wm = w >> 1, wn = w & 1;
    const int lr = lane & 15, lb = lane >> 4;

    for (int k0 = 0; k0 < KD; k0 += 32) {
        *(bf16x8*)&lAh[srow * 40 + scg * 8] =
            *(const bf16x8*)&Ah[(size_t)(row0 + srow) * lda + k0 + scg * 8];
        *(bf16x8*)&lAl[srow * 40 + scg * 8] =
            *(const bf16x8*)&Al[(size_t)(row0 + srow) * lda + k0 + scg * 8];
        *(bf16x8*)&lBh[srow * 40 + scg * 8] =
            *(const bf16x8*)&Bh[(size_t)(col0 + srow) * ldb + k0 + scg * 8];
        *(bf16x8*)&lBl[srow * 40 + scg * 8] =
            *(const bf16x8*)&Bl[(size_t)(col0 + srow) * ldb + k0 + scg * 8];
        __syncthreads();
        bf16x8 ah[2], al[2], bh[2], bl[2];
        #pragma unroll
        for (int mg = 0; mg < 2; ++mg) {
            const int r = wm * 32 + mg * 16 + lr;
            ah[mg] = *(const bf16x8*)&lAh[r * 40 + lb * 8];
            al[mg] = *(const bf16x8*)&lAl[r * 40 + lb * 8];
        }
        #pragma unroll
        for (int ng = 0; ng < 2; ++ng) {
            const int r = wn * 32 + ng * 16 + lr;
            bh[ng] = *(const bf16x8*)&lBh[r * 40 + lb * 8];
            bl[ng] = *(const bf16x8*)&lBl[r * 40 + lb * 8];
        }
        #pragma unroll
        for (int mg = 0; mg < 2; ++mg)
            #pragma unroll
            for (int ng = 0; ng < 2; ++ng) {
                acc[mg][ng] = mfma16(ah[mg], bh[ng], acc[mg][ng]);
                acc[mg][ng] = mfma16(al[mg], bh[ng], acc[mg][ng]);
                acc[mg][ng] = mfma16(ah[mg], bl[ng], acc[mg][ng]);
            }
        __syncthreads();
    }
}

// ---------------------------------------------------------------------------
// qkv GEMM; epilogue: Q (PRE-SCALED by log2e/sqrt(hd)) and K as bf16 hi/lo
// [head][n][hd]; V TRANSPOSED bf16 hi/lo into padded [head][PT][n]
// ---------------------------------------------------------------------------
template<int D>
__device__ void qkv_body(int bid, int tid,
                         const ush* __restrict__ xh, const ush* __restrict__ xl,
                         const ush* __restrict__ wh, const ush* __restrict__ wl,
                         ush* __restrict__ Qh, ush* __restrict__ Ql,
                         ush* __restrict__ Kh, ush* __restrict__ Kl,
                         ush* __restrict__ Vth, ush* __restrict__ Vtl, ush* lds) {
    constexpr int ds = DM_ / D;
    constexpr int hd = ds / H_;
    constexpr int PT = vpad_t<hd>::PT;
    constexpr int nx = 3 * ds / 64;
    const int bx = bid % nx, by = (bid / nx) & 7, bz = bid / (nx * 8);
    const int b = bz / D, d = bz % D;
    const int row0 = by * 64, col0 = bx * 64;
    const float SCQ = 1.44269504f * rsqrtf((float)hd);

    f32x4 acc[2][2] = {};
    gemm_core<ds>(xh + (size_t)b * N_ * DM_ + d * ds, xl + (size_t)b * N_ * DM_ + d * ds, DM_,
                  wh + (size_t)d * 3 * ds * ds, wl + (size_t)d * 3 * ds * ds, ds,
                  row0, col0, tid, lds, acc);

    const int lane = tid & 63, w = tid >> 6;
    const int wm = w >> 1, wn = w & 1;
    const int lr = lane & 15, lb = lane >> 4;
    #pragma unroll
    for (int mg = 0; mg < 2; ++mg)
        #pragma unroll
        for (int ng = 0; ng < 2; ++ng) {
            const int n0 = row0 + wm * 32 + mg * 16 + lb * 4;
            const int e  = col0 + wn * 32 + ng * 16 + lr;
            const int part = e / ds, ep = e % ds;
            const int h = ep / hd, t = ep % hd;
            const size_t head = ((size_t)b * D + d) * H_ + h;
            if (part == 2) {
                ush4 h4, l4;
                const float v0 = acc[mg][ng][0], v1 = acc[mg][ng][1];
                const float v2 = acc[mg][ng][2], v3 = acc[mg][ng][3];
                h4.x = f2bf(v0); l4.x = f2bf(v0 - bf2f(h4.x));
                h4.y = f2bf(v1); l4.y = f2bf(v1 - bf2f(h4.y));
                h4.z = f2bf(v2); l4.z = f2bf(v2 - bf2f(h4.z));
                h4.w = f2bf(v3); l4.w = f2bf(v3 - bf2f(h4.w));
                const size_t o = (head * PT + t) * N_ + n0;
                *(ush4*)&Vth[o] = h4;
                *(ush4*)&Vtl[o] = l4;
            } else {
                #pragma unroll
                for (int i = 0; i < 4; ++i) {
                    const size_t o = (head * N_ + n0 + i) * hd + t;
                    float v = acc[mg][ng][i];
                    if (part == 0) v *= SCQ;
                    const ush hh = f2bf(v), ll = f2bf(v - bf2f(hh));
                    if (part == 0) { Qh[o] = hh; Ql[o] = ll; }
                    else           { Kh[o] = hh; Kl[o] = ll; }
                }
            }
        }
}
__global__ __launch_bounds__(256) void k_qkv(
        const float* __restrict__ logits,
        const ush* __restrict__ xh, const ush* __restrict__ xl,
        const ush* __restrict__ wh, const ush* __restrict__ wl,
        ush* __restrict__ Qh, ush* __restrict__ Ql,
        ush* __restrict__ Kh, ush* __restrict__ Kl,
        ush* __restrict__ Vth, ush* __restrict__ Vtl) {
    __shared__ ush lds[4 * 2560];
    const int bid = blockIdx.x, tid = threadIdx.x;
    switch (sel_of(logits)) {
        case 0: qkv_body<1>(bid, tid, xh, xl, wh, wl, Qh, Ql, Kh, Kl, Vth, Vtl, lds); break;
        case 1: qkv_body<2>(bid, tid, xh, xl, wh, wl, Qh, Ql, Kh, Kl, Vth, Vtl, lds); break;
        case 2: qkv_body<4>(bid, tid, xh, xl, wh, wl, Qh, Ql, Kh, Kl, Vth, Vtl, lds); break;
        case 3: qkv_body<8>(bid, tid, xh, xl, wh, wl, Qh, Ql, Kh, Kl, Vth, Vtl, lds); break;
    }
}

// ---------------------------------------------------------------------------
// MFMA attention (exact round-10 structure, the 43.6us champion) with
// prescaled-Q adaptation: per-D kernels; 256-thread blocks of 4 FULLY
// INDEPENDENT waves; wave owns 16 q-rows x 512 k-cols in 16 chunks of 32.
// m=0 softmax (exp2 domain), denominator via V^T ones-column, P through a
// 16x40-ush wave-private LDS chunk. No barriers at all.
// ---------------------------------------------------------------------------
template<int D>
__device__ void attn_dev(int bid, int tid,
        const ush* __restrict__ Qh, const ush* __restrict__ Ql,
        const ush* __restrict__ Kh, const ush* __restrict__ Kl,
        const ush* __restrict__ Vth, const ush* __restrict__ Vtl,
        float* __restrict__ O, ush* Pall) {
    constexpr int ds = DM_ / D, hd = ds / H_;
    constexpr int CH  = (hd >= 64) ? 2 : 1;
    constexpr int NTP = (hd >= 16) ? hd / 16 + 1 : 1;   // PV tiles incl. l column
    constexpr int PT  = vpad_t<hd>::PT;
    constexpr int TL  = hd / 16;        // tile holding l column
    constexpr int LRL = hd % 16;        // lane (lr) holding l column
    constexpr int NBLK = B_ * D * H_ * 8;
    if (bid >= NBLK) return;
    const int bidr = (bid & 7) * (NBLK / 8) + (bid >> 3);
    const int w = tid >> 6;
    const int gw = bidr * 4 + w;
    const int head = gw >> 5, qt = gw & 31;
    const int h = head % H_, d = (head / H_) % D, b = head / (H_ * D);
    const int q0 = qt * 16;
    const size_t hbq = (size_t)head * N_ * hd;
    const size_t hbv = (size_t)head * PT * N_;
    const int lane = tid & 63, lr = lane & 15, lb = lane >> 4;
    ush* Pc = Pall + w * 16 * 40;        // [16 rows][40 ush] wave-private
    const float RB2 = LAM_ * (2.0f / N_) * 1.44269504f;
    const bf16x8 z8 = {0, 0, 0, 0, 0, 0, 0, 0};

    // Q fragment (B-operand, prescaled): lane holds q-row q0+lr, k-slice lb*8
    bf16x8 qah[CH], qal[CH];
    #pragma unroll
    for (int c = 0; c < CH; ++c) {
        const int k0 = c * 32 + lb * 8;
        bf16x8 vh = z8, vl = z8;
        if (k0 < hd) {
            const size_t o = hbq + (size_t)(q0 + lr) * hd + k0;
            vh = *(const bf16x8*)&Qh[o];
            vl = *(const bf16x8*)&Ql[o];
        }
        qah[c] = vh; qal[c] = vl;
    }

    const int q = q0 + lr;
    f32x4 acc2[NTP];
    #pragma unroll
    for (int tt = 0; tt < NTP; ++tt) acc2[tt] = (f32x4){0.f, 0.f, 0.f, 0.f};

    for (int ck = 0; ck < 16; ++ck) {
        const int col0 = ck * 32;

        // S^T = K Q^T for 2 tiles (32 k-cols), already log2-scaled
        f32x4 s0 = {0.f, 0.f, 0.f, 0.f}, s1 = {0.f, 0.f, 0.f, 0.f};
        #pragma unroll
        for (int c = 0; c < CH; ++c) {
            const int k0 = c * 32 + lb * 8;
            bf16x8 k0h = z8, k0l = z8, k1h = z8, k1l = z8;
            if (k0 < hd) {
                const size_t o0 = hbq + (size_t)(col0 + lr) * hd + k0;
                const size_t o1 = hbq + (size_t)(col0 + 16 + lr) * hd + k0;
                k0h = *(const bf16x8*)&Kh[o0]; k0l = *(const bf16x8*)&Kl[o0];
                k1h = *(const bf16x8*)&Kh[o1]; k1l = *(const bf16x8*)&Kl[o1];
            }
            s0 = mfma16(k0h, qah[c], s0);
            s0 = mfma16(k0l, qah[c], s0);
            s0 = mfma16(k0h, qal[c], s0);
            s1 = mfma16(k1h, qah[c], s1);
            s1 = mfma16(k1l, qah[c], s1);
            s1 = mfma16(k1h, qal[c], s1);
        }

        // exp2(s - RB2*ring) -> packed bf16 -> LDS (2 x 8B per lane)
        #pragma unroll
        for (int t = 0; t < 2; ++t) {
            const f32x4 sv = t ? s1 : s0;
            const int kbase = col0 + t * 16 + lb * 4;
            float p[4];
            #pragma unroll
            for (int i = 0; i < 4; ++i) {
                int dd = q - (kbase + i); dd = dd < 0 ? -dd : dd;
                const int ring = (dd < N_ - dd) ? dd : (N_ - dd);
                p[i] = exp2f(sv[i] - RB2 * (float)ring);
            }
            unsigned pk0, pk1;
            asm("v_cvt_pk_bf16_f32 %0, %1, %2" : "=v"(pk0) : "v"(p[0]), "v"(p[1]));
            asm("v_cvt_pk_bf16_f32 %0, %1, %2" : "=v"(pk1) : "v"(p[2]), "v"(p[3]));
            uint2s pv; pv.x = pk0; pv.y = pk1;
            *(uint2s*)((char*)Pc + lr * 80 + t * 32 + lb * 8) = pv;
        }

        // PV for this 32-col chunk (A = P row fragment straight from LDS)
        const bf16x8 pa = *(const bf16x8*)((const char*)Pc + lr * 80 + lb * 16);
        #pragma unroll
        for (int tt = 0; tt < NTP; ++tt) {
            const size_t o = hbv + (size_t)(tt * 16 + lr) * N_ + col0 + lb * 8;
            const bf16x8 vh8 = *(const bf16x8*)&Vth[o];
            const bf16x8 vl8 = *(const bf16x8*)&Vtl[o];
            acc2[tt] = mfma16(pa, vh8, acc2[tt]);
            acc2[tt] = mfma16(pa, vl8, acc2[tt]);
        }
    }

    // l = PV ones-column at (tile TL, lane LRL); redistribute per output row
    float linv[4];
    #pragma unroll
    for (int i = 0; i < 4; ++i)
        linv[i] = 1.0f / __shfl(acc2[TL][i], (lane & 48) | LRL);

    #pragma unroll
    for (int tt = 0; tt < NTP; ++tt)
        #pragma unroll
        for (int i = 0; i < 4; ++i) {
            const int rn = q0 + lb * 4 + i;
            const int tc = tt * 16 + lr;
            if (tc < hd)
                O[((size_t)b * N_ + rn) * DM_ + d * ds + h * hd + tc] = acc2[tt][i] * linv[i];
        }
}
#define DEF_ATTN(NAME, DD, BR)                                                \
__global__ __launch_bounds__(256) void NAME(                                  \
        const float* __restrict__ logits,                                     \
        const ush* __restrict__ Qh, const ush* __restrict__ Ql,               \
        const ush* __restrict__ Kh, const ush* __restrict__ Kl,               \
        const ush* __restrict__ Vth, const ush* __restrict__ Vtl,             \
        float* __restrict__ O) {                                              \
    __shared__ __align__(16) ush Pc[4 * 16 * 40];                             \
    if (sel_of(logits) != BR) return;                                         \
    attn_dev<DD>(blockIdx.x, threadIdx.x, Qh, Ql, Kh, Kl, Vth, Vtl, O, Pc);   \
}
DEF_ATTN(k_attn_1, 1, 0)
DEF_ATTN(k_attn_2, 2, 1)
DEF_ATTN(k_attn_4, 4, 2)
DEF_ATTN(k_attn_8, 8, 3)

// ---------------------------------------------------------------------------
// out = (mix ⊗ O) @ wo — k_mix FUSED into the A-tile staging.
// 32x64 tiles, grid 512. mix[D][D] computed once per block in LDS;
// F[r][k] = sum_f mix[d(k),f] * O[r][f*ds + s(k)] computed on the fly,
// split to bf16 hi/lo in LDS.
// ---------------------------------------------------------------------------
__global__ __launch_bounds__(256) void k_wo(
        const float* __restrict__ logits,
        const float* __restrict__ fu0, const float* __restrict__ fv0,
        const float* __restrict__ fu1, const float* __restrict__ fv1,
        const float* __restrict__ fu2, const float* __restrict__ fv2,
        const float* __restrict__ fu3, const float* __restrict__ fv3,
        const float* __restrict__ O,
        const ush* __restrict__ wh, const ush* __restrict__ wl,
        float* __restrict__ out) {
    __shared__ ush lA[2][32 * 40];
    __shared__ ush lB[2][64 * 40];
    __shared__ float mixs[64];
    const int tid = threadIdx.x;
    const int s = sel_of(logits);
    int Dv, dsh;
    const float *fu, *fv;
    switch (s) {
        case 0:  Dv = 1; dsh = 10; fu = fu0; fv = fv0; break;
        case 1:  Dv = 2; dsh = 9;  fu = fu1; fv = fv1; break;
        case 2:  Dv = 4; dsh = 8;  fu = fu2; fv = fv2; break;
        default: Dv = 8; dsh = 7;  fu = fu3; fv = fv3; break;
    }
    const int Rv = (Dv / 4 > 0) ? (Dv / 4) : 1;
    const int dmask = (1 << dsh) - 1;
    if (tid < Dv * Dv) {
        const int d = tid / Dv, f = tid % Dv;
        float m = 0.f;
        for (int rr = 0; rr < Rv; ++rr) m += fu[d * Rv + rr] * fv[rr * Dv + f];
        mixs[tid] = m;
    }
    __syncthreads();

    const int bx = blockIdx.x & 15, by = blockIdx.x >> 4;
    const int row0 = by * 32, col0 = bx * 64;
    const int lane = tid & 63, w = tid >> 6;
    const int wq = w >> 1, wn = w & 1;
    const int lr = lane & 15, lb = lane >> 4;
    f32x4 acc[2] = {};

    for (int k0 = 0; k0 < DM_; k0 += 32) {
        if (tid < 128) {   // A: compute F on the fly, split hi/lo
            const int srow = tid >> 2, scg = tid & 3;
            const float* Orow = O + (size_t)(row0 + srow) * DM_;
            bf16x8 hv, lv;
            #pragma unroll
            for (int j = 0; j < 8; ++j) {
                const int kk = k0 + scg * 8 + j;
                const int dd = kk >> dsh, ss = kk & dmask;
                float a = 0.f;
                for (int f = 0; f < Dv; ++f)
                    a += mixs[dd * Dv + f] * Orow[(f << dsh) + ss];
                const ush hh = f2bf(a);
                hv[j] = (short)hh;
                lv[j] = (short)f2bf(a - bf2f(hh));
            }
            *(bf16x8*)&lA[0][srow * 40 + scg * 8] = hv;
            *(bf16x8*)&lA[1][srow * 40 + scg * 8] = lv;
        }
        {   // B: all 256 threads stage hi then lo
            const int srow = tid >> 2, scg = tid & 3;
            *(bf16x8*)&lB[0][srow * 40 + scg * 8] =
                *(const bf16x8*)&wh[(size_t)(col0 + srow) * DM_ + k0 + scg * 8];
            *(bf16x8*)&lB[1][srow * 40 + scg * 8] =
                *(const bf16x8*)&wl[(size_t)(col0 + srow) * DM_ + k0 + scg * 8];
        }
        __syncthreads();
        const int ar = wq * 16 + lr;
        const bf16x8 ah = *(const bf16x8*)&lA[0][ar * 40 + lb * 8];
        const bf16x8 al = *(const bf16x8*)&lA[1][ar * 40 + lb * 8];
        #pragma unroll
        for (int ng = 0; ng < 2; ++ng) {
            const int br = wn * 32 + ng * 16 + lr;
            const bf16x8 bh = *(const bf16x8*)&lB[0][br * 40 + lb * 8];
            const bf16x8 bl = *(const bf16x8*)&lB[1][br * 40 + lb * 8];
            acc[ng] = mfma16(ah, bh, acc[ng]);
            acc[ng] = mfma16(al, bh, acc[ng]);
            acc[ng] = mfma16(ah, bl, acc[ng]);
        }
        __syncthreads();
    }
    #pragma unroll
    for (int ng = 0; ng < 2; ++ng)
        #pragma unroll
        for (int i = 0; i < 4; ++i) {
            const int r = row0 + wq * 16 + lb * 4 + i;
            const int c = col0 + wn * 32 + ng * 16 + lr;
            out[(size_t)r * DM_ + c] = acc[ng][i];
        }
}

// ---------------------------------------------------------------------------
extern "C" void kernel_launch(void* const* d_in, const int* in_sizes, int n_in,
                              void* d_out, int out_size, void* d_ws, size_t ws_size,
                              hipStream_t stream) {
    const float* x      = (const float*)d_in[0];
    const float* logits = (const float*)d_in[1];
    float* out = (float*)d_out;

    char* p = (char*)d_ws;
    p += 256;
    const size_t MB = 1024 * 1024;
    ush* Qh = (ush*)p; p += 2 * MB;
    ush* Ql = (ush*)p; p += 2 * MB;
    ush* Kh = (ush*)p; p += 2 * MB;
    ush* Kl = (ush*)p; p += 2 * MB;
    ush* Vth = (ush*)p; p += 4 * MB;           // padded V^T
    ush* Vtl = (ush*)p; p += 4 * MB;
    float* O = (float*)p; p += 4 * MB;
    ush* xh = (ush*)p; p += 2 * MB;
    ush* xl = (ush*)p; p += 2 * MB;
    ush* wqh = (ush*)p; p += 6 * MB;
    ush* wql = (ush*)p; p += 6 * MB;
    ush* woh = (ush*)p; p += 2 * MB;
    ush* wol = (ush*)p; p += 2 * MB;

    k_prep<<<dim3(3072), dim3(256), 0, stream>>>(
        logits, x,
        (const float*)d_in[2], (const float*)d_in[7],
        (const float*)d_in[12], (const float*)d_in[17],
        (const float*)d_in[3], (const float*)d_in[8],
        (const float*)d_in[13], (const float*)d_in[18],
        (const float*)d_in[4], (const float*)d_in[9],
        (const float*)d_in[14], (const float*)d_in[19],
        xh, xl, wqh, wql, woh, wol, Vth, Vtl);
    k_qkv<<<dim3(768), dim3(256), 0, stream>>>(logits, xh, xl, wqh, wql,
                                               Qh, Ql, Kh, Kl, Vth, Vtl);
    k_attn_1<<<dim3(256),  dim3(256), 0, stream>>>(logits, Qh, Ql, Kh, Kl, Vth, Vtl, O);
    k_attn_2<<<dim3(512),  dim3(256), 0, stream>>>(logits, Qh, Ql, Kh, Kl, Vth, Vtl, O);
    k_attn_4<<<dim3(1024), dim3(256), 0, stream>>>(logits, Qh, Ql, Kh, Kl, Vth, Vtl, O);
    k_attn_8<<<dim3(2048), dim3(256), 0, stream>>>(logits, Qh, Ql, Kh, Kl, Vth, Vtl, O);
    k_wo<<<dim3(512), dim3(256), 0, stream>>>(
        logits,
        (const float*)d_in[5],  (const float*)d_in[6],
        (const float*)d_in[10], (const float*)d_in[11],
        (const float*)d_in[15], (const float*)d_in[16],
        (const float*)d_in[20], (const float*)d_in[21],
        O, woh, wol, out);
}

// Round 15
// 94.381 us; speedup vs baseline: 2.2868x; 2.2868x over previous
//
#include <hip/hip_runtime.h>

#define B_   2
#define N_   512
#define DM_  1024
#define H_   16
#define LAM_ 0.1f

typedef __attribute__((ext_vector_type(8))) short bf16x8;
typedef __attribute__((ext_vector_type(4))) float f32x4;
typedef unsigned short ush;
struct ush4 { ush x, y, z, w; };
struct uint2s { unsigned x, y; };

__device__ inline ush f2bf(float v) {
    union { float f; unsigned u; } c; c.f = v;
    unsigned r = c.u + 0x7FFF + ((c.u >> 16) & 1);
    return (ush)(r >> 16);
}
__device__ inline float bf2f(ush b) {
    union { float f; unsigned u; } c; c.u = ((unsigned)b) << 16; return c.f;
}
__device__ inline f32x4 mfma16(bf16x8 a, bf16x8 b, f32x4 c) {
    return __builtin_amdgcn_mfma_f32_16x16x32_bf16(a, b, c, 0, 0, 0);
}
// jnp.argmax semantics (first max wins); uniform -> scalar loads
__device__ inline int sel_of(const float* __restrict__ lg) {
    float b = lg[0]; int s = 0;
    if (lg[1] > b) { b = lg[1]; s = 1; }
    if (lg[2] > b) { b = lg[2]; s = 2; }
    if (lg[3] > b) { b = lg[3]; s = 3; }
    return s;
}

// V^T padded stride per head: data rows [0,hd), ones row at hd, zeros to PT
template<int HD> struct vpad_t { static constexpr int PT = (HD >= 16) ? HD + 16 : 16; };

// ---------------------------------------------------------------------------
// fused prep. Region map (256-thread blocks):
//   [0,    1024): x+pe -> bf16 hi/lo, float4-vectorized
//   [1024, 1792): wqkv transpose, 64x64 LDS tiles
//   [1792, 2048): wo transpose, 64x64 LDS tiles
//   [2048, 3072): V^T pad fill (ones row at hd, zeros above)
// ---------------------------------------------------------------------------
template<int D>
__device__ void prep_wt_tile(int bT, int tid, const float* __restrict__ w,
                             ush* __restrict__ wh, ush* __restrict__ wl,
                             float (*lds)[65]) {
    constexpr int ds = DM_ / D;
    constexpr int tpr = 3 * ds / 64;
    constexpr int tpc = ds / 64;
    constexpr int tpd = tpr * tpc;
    if (bT >= D * tpd) return;
    const int d = bT / tpd, rem = bT % tpd;
    const int tr = rem / tpr, tc = rem % tpr;
    const float* src = w + (size_t)d * ds * 3 * ds;
    ush* dsth = wh + (size_t)d * 3 * ds * ds;
    ush* dstl = wl + (size_t)d * 3 * ds * ds;
    const int c = tid & 63, r0 = tid >> 6;
    #pragma unroll
    for (int j = 0; j < 16; ++j) {
        const int r = j * 4 + r0;
        lds[r][c] = src[(size_t)(tr * 64 + r) * (3 * ds) + tc * 64 + c];
    }
    __syncthreads();
    #pragma unroll
    for (int j = 0; j < 16; ++j) {
        const int r = j * 4 + r0;
        const float v = lds[c][r];
        const size_t o = (size_t)(tc * 64 + r) * ds + tr * 64 + c;
        const ush h = f2bf(v);
        dsth[o] = h; dstl[o] = f2bf(v - bf2f(h));
    }
}
template<int D>
__device__ void prep_vpad(int bT, int tid, ush* __restrict__ Vth, ush* __restrict__ Vtl) {
    constexpr int ds = DM_ / D, hd = ds / H_;
    constexpr int PT = vpad_t<hd>::PT;
    constexpr int NH = B_ * D * H_;
    constexpr int PR = PT - hd;
    constexpr int TOT = NH * PR * (N_ / 4);
    const int g = bT * 256 + tid;
    if (g >= TOT) return;
    constexpr int perh = PR * (N_ / 4);
    const int head = g / perh, rem = g % perh;
    const int r = hd + rem / (N_ / 4), n4 = (rem % (N_ / 4)) * 4;
    const size_t o = ((size_t)head * PT + r) * N_ + n4;
    const ush one = (r == hd) ? (ush)0x3F80 : (ush)0;
    ush4 hv; hv.x = one; hv.y = one; hv.z = one; hv.w = one;
    ush4 zv; zv.x = 0; zv.y = 0; zv.z = 0; zv.w = 0;
    *(ush4*)&Vth[o] = hv;
    *(ush4*)&Vtl[o] = zv;
}
__global__ __launch_bounds__(256) void k_prep(
        const float* __restrict__ logits, const float* __restrict__ x,
        const float* __restrict__ pe0, const float* __restrict__ pe1,
        const float* __restrict__ pe2, const float* __restrict__ pe3,
        const float* __restrict__ w0, const float* __restrict__ w1,
        const float* __restrict__ w2, const float* __restrict__ w3,
        const float* __restrict__ wo0, const float* __restrict__ wo1,
        const float* __restrict__ wo2, const float* __restrict__ wo3,
        ush* __restrict__ xh, ush* __restrict__ xl,
        ush* __restrict__ wqh, ush* __restrict__ wql,
        ush* __restrict__ woh, ush* __restrict__ wol,
        ush* __restrict__ Vth, ush* __restrict__ Vtl) {
    __shared__ float lds[64][65];
    const int s = sel_of(logits);
    const int bid = blockIdx.x, tid = threadIdx.x;
    if (bid < 1024) {
        const float* pe = (s == 0) ? pe0 : (s == 1) ? pe1 : (s == 2) ? pe2 : pe3;
        const size_t i0 = ((size_t)bid * 256 + tid) * 4;
        const float4 xv = *(const float4*)&x[i0];
        const float4 pv = *(const float4*)&pe[i0 & ((size_t)N_ * DM_ - 1)];
        ush4 h4, l4;
        float v;
        v = xv.x + pv.x; h4.x = f2bf(v); l4.x = f2bf(v - bf2f(h4.x));
        v = xv.y + pv.y; h4.y = f2bf(v); l4.y = f2bf(v - bf2f(h4.y));
        v = xv.z + pv.z; h4.z = f2bf(v); l4.z = f2bf(v - bf2f(h4.z));
        v = xv.w + pv.w; h4.w = f2bf(v); l4.w = f2bf(v - bf2f(h4.w));
        *(ush4*)&xh[i0] = h4;
        *(ush4*)&xl[i0] = l4;
    } else if (bid < 1792) {
        const int bT = bid - 1024;
        switch (s) {
            case 0: prep_wt_tile<1>(bT, tid, w0, wqh, wql, lds); break;
            case 1: prep_wt_tile<2>(bT, tid, w1, wqh, wql, lds); break;
            case 2: prep_wt_tile<4>(bT, tid, w2, wqh, wql, lds); break;
            case 3: prep_wt_tile<8>(bT, tid, w3, wqh, wql, lds); break;
        }
    } else if (bid < 2048) {
        const float* w = (s == 0) ? wo0 : (s == 1) ? wo1 : (s == 2) ? wo2 : wo3;
        const int bT = bid - 1792;
        const int tr = bT >> 4, tc = bT & 15;
        const int c = tid & 63, r0 = tid >> 6;
        #pragma unroll
        for (int j = 0; j < 16; ++j) {
            const int r = j * 4 + r0;
            lds[r][c] = w[(size_t)(tr * 64 + r) * DM_ + tc * 64 + c];
        }
        __syncthreads();
        #pragma unroll
        for (int j = 0; j < 16; ++j) {
            const int r = j * 4 + r0;
            const float v = lds[c][r];
            const size_t o = (size_t)(tc * 64 + r) * DM_ + tr * 64 + c;
            const ush h = f2bf(v);
            woh[o] = h; wol[o] = f2bf(v - bf2f(h));
        }
    } else {
        const int bT = bid - 2048;
        switch (s) {
            case 0: prep_vpad<1>(bT, tid, Vth, Vtl); break;
            case 1: prep_vpad<2>(bT, tid, Vth, Vtl); break;
            case 2: prep_vpad<4>(bT, tid, Vth, Vtl); break;
            case 3: prep_vpad<8>(bT, tid, Vth, Vtl); break;
        }
    }
}

// ---------------------------------------------------------------------------
// Split-bf16 MFMA GEMM core (64x64 tile, BK=32, 4 waves) — used by k_qkv
// ---------------------------------------------------------------------------
template<int KD>
__device__ void gemm_core(const ush* __restrict__ Ah, const ush* __restrict__ Al, int lda,
                          const ush* __restrict__ Bh, const ush* __restrict__ Bl, int ldb,
                          int row0, int col0, int tid, ush* lds, f32x4 acc[2][2]) {
    ush* lAh = lds; ush* lAl = lds + 2560; ush* lBh = lds + 5120; ush* lBl = lds + 7680;
    const int srow = tid >> 2, scg = tid & 3;
    const int lane = tid & 63, w = tid >> 6;
    const int wm = w >> 1, wn = w & 1;
    const int lr = lane & 15, lb = lane >> 4;

    for (int k0 = 0; k0 < KD; k0 += 32) {
        *(bf16x8*)&lAh[srow * 40 + scg * 8] =
            *(const bf16x8*)&Ah[(size_t)(row0 + srow) * lda + k0 + scg * 8];
        *(bf16x8*)&lAl[srow * 40 + scg * 8] =
            *(const bf16x8*)&Al[(size_t)(row0 + srow) * lda + k0 + scg * 8];
        *(bf16x8*)&lBh[srow * 40 + scg * 8] =
            *(const bf16x8*)&Bh[(size_t)(col0 + srow) * ldb + k0 + scg * 8];
        *(bf16x8*)&lBl[srow * 40 + scg * 8] =
            *(const bf16x8*)&Bl[(size_t)(col0 + srow) * ldb + k0 + scg * 8];
        __syncthreads();
        bf16x8 ah[2], al[2], bh[2], bl[2];
        #pragma unroll
        for (int mg = 0; mg < 2; ++mg) {
            const int r = wm * 32 + mg * 16 + lr;
            ah[mg] = *(const bf16x8*)&lAh[r * 40 + lb * 8];
            al[mg] = *(const bf16x8*)&lAl[r * 40 + lb * 8];
        }
        #pragma unroll
        for (int ng = 0; ng < 2; ++ng) {
            const int r = wn * 32 + ng * 16 + lr;
            bh[ng] = *(const bf16x8*)&lBh[r * 40 + lb * 8];
            bl[ng] = *(const bf16x8*)&lBl[r * 40 + lb * 8];
        }
        #pragma unroll
        for (int mg = 0; mg < 2; ++mg)
            #pragma unroll
            for (int ng = 0; ng < 2; ++ng) {
                acc[mg][ng] = mfma16(ah[mg], bh[ng], acc[mg][ng]);
                acc[mg][ng] = mfma16(al[mg], bh[ng], acc[mg][ng]);
                acc[mg][ng] = mfma16(ah[mg], bl[ng], acc[mg][ng]);
            }
        __syncthreads();
    }
}

// ---------------------------------------------------------------------------
// qkv GEMM; epilogue: Q (PRE-SCALED by log2e/sqrt(hd)) and K as bf16 hi/lo
// [head][n][hd]; V TRANSPOSED bf16 hi/lo into padded [head][PT][n]
// ---------------------------------------------------------------------------
template<int D>
__device__ void qkv_body(int bid, int tid,
                         const ush* __restrict__ xh, const ush* __restrict__ xl,
                         const ush* __restrict__ wh, const ush* __restrict__ wl,
                         ush* __restrict__ Qh, ush* __restrict__ Ql,
                         ush* __restrict__ Kh, ush* __restrict__ Kl,
                         ush* __restrict__ Vth, ush* __restrict__ Vtl, ush* lds) {
    constexpr int ds = DM_ / D;
    constexpr int hd = ds / H_;
    constexpr int PT = vpad_t<hd>::PT;
    constexpr int nx = 3 * ds / 64;
    const int bx = bid % nx, by = (bid / nx) & 7, bz = bid / (nx * 8);
    const int b = bz / D, d = bz % D;
    const int row0 = by * 64, col0 = bx * 64;
    const float SCQ = 1.44269504f * rsqrtf((float)hd);

    f32x4 acc[2][2] = {};
    gemm_core<ds>(xh + (size_t)b * N_ * DM_ + d * ds, xl + (size_t)b * N_ * DM_ + d * ds, DM_,
                  wh + (size_t)d * 3 * ds * ds, wl + (size_t)d * 3 * ds * ds, ds,
                  row0, col0, tid, lds, acc);

    const int lane = tid & 63, w = tid >> 6;
    const int wm = w >> 1, wn = w & 1;
    const int lr = lane & 15, lb = lane >> 4;
    #pragma unroll
    for (int mg = 0; mg < 2; ++mg)
        #pragma unroll
        for (int ng = 0; ng < 2; ++ng) {
            const int n0 = row0 + wm * 32 + mg * 16 + lb * 4;
            const int e  = col0 + wn * 32 + ng * 16 + lr;
            const int part = e / ds, ep = e % ds;
            const int h = ep / hd, t = ep % hd;
            const size_t head = ((size_t)b * D + d) * H_ + h;
            if (part == 2) {
                ush4 h4, l4;
                const float v0 = acc[mg][ng][0], v1 = acc[mg][ng][1];
                const float v2 = acc[mg][ng][2], v3 = acc[mg][ng][3];
                h4.x = f2bf(v0); l4.x = f2bf(v0 - bf2f(h4.x));
                h4.y = f2bf(v1); l4.y = f2bf(v1 - bf2f(h4.y));
                h4.z = f2bf(v2); l4.z = f2bf(v2 - bf2f(h4.z));
                h4.w = f2bf(v3); l4.w = f2bf(v3 - bf2f(h4.w));
                const size_t o = (head * PT + t) * N_ + n0;
                *(ush4*)&Vth[o] = h4;
                *(ush4*)&Vtl[o] = l4;
            } else {
                #pragma unroll
                for (int i = 0; i < 4; ++i) {
                    const size_t o = (head * N_ + n0 + i) * hd + t;
                    float v = acc[mg][ng][i];
                    if (part == 0) v *= SCQ;
                    const ush hh = f2bf(v), ll = f2bf(v - bf2f(hh));
                    if (part == 0) { Qh[o] = hh; Ql[o] = ll; }
                    else           { Kh[o] = hh; Kl[o] = ll; }
                }
            }
        }
}
__global__ __launch_bounds__(256) void k_qkv(
        const float* __restrict__ logits,
        const ush* __restrict__ xh, const ush* __restrict__ xl,
        const ush* __restrict__ wh, const ush* __restrict__ wl,
        ush* __restrict__ Qh, ush* __restrict__ Ql,
        ush* __restrict__ Kh, ush* __restrict__ Kl,
        ush* __restrict__ Vth, ush* __restrict__ Vtl) {
    __shared__ ush lds[4 * 2560];
    const int bid = blockIdx.x, tid = threadIdx.x;
    switch (sel_of(logits)) {
        case 0: qkv_body<1>(bid, tid, xh, xl, wh, wl, Qh, Ql, Kh, Kl, Vth, Vtl, lds); break;
        case 1: qkv_body<2>(bid, tid, xh, xl, wh, wl, Qh, Ql, Kh, Kl, Vth, Vtl, lds); break;
        case 2: qkv_body<4>(bid, tid, xh, xl, wh, wl, Qh, Ql, Kh, Kl, Vth, Vtl, lds); break;
        case 3: qkv_body<8>(bid, tid, xh, xl, wh, wl, Qh, Ql, Kh, Kl, Vth, Vtl, lds); break;
    }
}

// ---------------------------------------------------------------------------
// MFMA attention (round-10 champion structure + prescaled Q): per-D kernels;
// 256-thread blocks of 4 FULLY INDEPENDENT waves; wave owns 16 q-rows x 512
// k-cols in 16 chunks of 32. m=0 softmax (exp2 domain), denominator via V^T
// ones-column, P through a 16x40-ush wave-private LDS chunk. No barriers.
// ---------------------------------------------------------------------------
template<int D>
__device__ void attn_dev(int bid, int tid,
        const ush* __restrict__ Qh, const ush* __restrict__ Ql,
        const ush* __restrict__ Kh, const ush* __restrict__ Kl,
        const ush* __restrict__ Vth, const ush* __restrict__ Vtl,
        float* __restrict__ O, ush* Pall) {
    constexpr int ds = DM_ / D, hd = ds / H_;
    constexpr int CH  = (hd >= 64) ? 2 : 1;
    constexpr int NTP = (hd >= 16) ? hd / 16 + 1 : 1;   // PV tiles incl. l column
    constexpr int PT  = vpad_t<hd>::PT;
    constexpr int TL  = hd / 16;        // tile holding l column
    constexpr int LRL = hd % 16;        // lane (lr) holding l column
    constexpr int NBLK = B_ * D * H_ * 8;
    if (bid >= NBLK) return;
    const int bidr = (bid & 7) * (NBLK / 8) + (bid >> 3);
    const int w = tid >> 6;
    const int gw = bidr * 4 + w;
    const int head = gw >> 5, qt = gw & 31;
    const int h = head % H_, d = (head / H_) % D, b = head / (H_ * D);
    const int q0 = qt * 16;
    const size_t hbq = (size_t)head * N_ * hd;
    const size_t hbv = (size_t)head * PT * N_;
    const int lane = tid & 63, lr = lane & 15, lb = lane >> 4;
    ush* Pc = Pall + w * 16 * 40;        // [16 rows][40 ush] wave-private
    const float RB2 = LAM_ * (2.0f / N_) * 1.44269504f;
    const bf16x8 z8 = {0, 0, 0, 0, 0, 0, 0, 0};

    // Q fragment (B-operand, prescaled): lane holds q-row q0+lr, k-slice lb*8
    bf16x8 qah[CH], qal[CH];
    #pragma unroll
    for (int c = 0; c < CH; ++c) {
        const int k0 = c * 32 + lb * 8;
        bf16x8 vh = z8, vl = z8;
        if (k0 < hd) {
            const size_t o = hbq + (size_t)(q0 + lr) * hd + k0;
            vh = *(const bf16x8*)&Qh[o];
            vl = *(const bf16x8*)&Ql[o];
        }
        qah[c] = vh; qal[c] = vl;
    }

    const int q = q0 + lr;
    f32x4 acc2[NTP];
    #pragma unroll
    for (int tt = 0; tt < NTP; ++tt) acc2[tt] = (f32x4){0.f, 0.f, 0.f, 0.f};

    for (int ck = 0; ck < 16; ++ck) {
        const int col0 = ck * 32;

        // S^T = K Q^T for 2 tiles (32 k-cols), already log2-scaled
        f32x4 s0 = {0.f, 0.f, 0.f, 0.f}, s1 = {0.f, 0.f, 0.f, 0.f};
        #pragma unroll
        for (int c = 0; c < CH; ++c) {
            const int k0 = c * 32 + lb * 8;
            bf16x8 k0h = z8, k0l = z8, k1h = z8, k1l = z8;
            if (k0 < hd) {
                const size_t o0 = hbq + (size_t)(col0 + lr) * hd + k0;
                const size_t o1 = hbq + (size_t)(col0 + 16 + lr) * hd + k0;
                k0h = *(const bf16x8*)&Kh[o0]; k0l = *(const bf16x8*)&Kl[o0];
                k1h = *(const bf16x8*)&Kh[o1]; k1l = *(const bf16x8*)&Kl[o1];
            }
            s0 = mfma16(k0h, qah[c], s0);
            s0 = mfma16(k0l, qah[c], s0);
            s0 = mfma16(k0h, qal[c], s0);
            s1 = mfma16(k1h, qah[c], s1);
            s1 = mfma16(k1l, qah[c], s1);
            s1 = mfma16(k1h, qal[c], s1);
        }

        // exp2(s - RB2*ring) -> packed bf16 -> LDS (2 x 8B per lane)
        #pragma unroll
        for (int t = 0; t < 2; ++t) {
            const f32x4 sv = t ? s1 : s0;
            const int kbase = col0 + t * 16 + lb * 4;
            float p[4];
            #pragma unroll
            for (int i = 0; i < 4; ++i) {
                int dd = q - (kbase + i); dd = dd < 0 ? -dd : dd;
                const int ring = (dd < N_ - dd) ? dd : (N_ - dd);
                p[i] = exp2f(sv[i] - RB2 * (float)ring);
            }
            unsigned pk0, pk1;
            asm("v_cvt_pk_bf16_f32 %0, %1, %2" : "=v"(pk0) : "v"(p[0]), "v"(p[1]));
            asm("v_cvt_pk_bf16_f32 %0, %1, %2" : "=v"(pk1) : "v"(p[2]), "v"(p[3]));
            uint2s pv; pv.x = pk0; pv.y = pk1;
            *(uint2s*)((char*)Pc + lr * 80 + t * 32 + lb * 8) = pv;
        }

        // PV for this 32-col chunk (A = P row fragment straight from LDS)
        const bf16x8 pa = *(const bf16x8*)((const char*)Pc + lr * 80 + lb * 16);
        #pragma unroll
        for (int tt = 0; tt < NTP; ++tt) {
            const size_t o = hbv + (size_t)(tt * 16 + lr) * N_ + col0 + lb * 8;
            const bf16x8 vh8 = *(const bf16x8*)&Vth[o];
            const bf16x8 vl8 = *(const bf16x8*)&Vtl[o];
            acc2[tt] = mfma16(pa, vh8, acc2[tt]);
            acc2[tt] = mfma16(pa, vl8, acc2[tt]);
        }
    }

    // l = PV ones-column at (tile TL, lane LRL); redistribute per output row
    float linv[4];
    #pragma unroll
    for (int i = 0; i < 4; ++i)
        linv[i] = 1.0f / __shfl(acc2[TL][i], (lane & 48) | LRL);

    #pragma unroll
    for (int tt = 0; tt < NTP; ++tt)
        #pragma unroll
        for (int i = 0; i < 4; ++i) {
            const int rn = q0 + lb * 4 + i;
            const int tc = tt * 16 + lr;
            if (tc < hd)
                O[((size_t)b * N_ + rn) * DM_ + d * ds + h * hd + tc] = acc2[tt][i] * linv[i];
        }
}
#define DEF_ATTN(NAME, DD, BR)                                                \
__global__ __launch_bounds__(256) void NAME(                                  \
        const float* __restrict__ logits,                                     \
        const ush* __restrict__ Qh, const ush* __restrict__ Ql,               \
        const ush* __restrict__ Kh, const ush* __restrict__ Kl,               \
        const ush* __restrict__ Vth, const ush* __restrict__ Vtl,             \
        float* __restrict__ O) {                                              \
    __shared__ __align__(16) ush Pc[4 * 16 * 40];                             \
    if (sel_of(logits) != BR) return;                                         \
    attn_dev<DD>(blockIdx.x, threadIdx.x, Qh, Ql, Kh, Kl, Vth, Vtl, O, Pc);   \
}
DEF_ATTN(k_attn_1, 1, 0)
DEF_ATTN(k_attn_2, 2, 1)
DEF_ATTN(k_attn_4, 4, 2)
DEF_ATTN(k_attn_8, 8, 3)

// ---------------------------------------------------------------------------
// depth mix: F = einsum(mix, O) -> bf16 hi/lo (round-13 version, streaming)
// ---------------------------------------------------------------------------
template<int D>
__device__ void mix_body(int bid, int tid, const float* __restrict__ fu,
                         const float* __restrict__ fv, const float* __restrict__ O,
                         ush* __restrict__ Fh, ush* __restrict__ Fl, float* mixs) {
    constexpr int ds = DM_ / D;
    constexpr int R = (D / 4 > 0) ? (D / 4) : 1;
    if (tid < D * D) {
        const int d = tid / D, f = tid % D;
        float m = 0.f;
        #pragma unroll
        for (int rr = 0; rr < R; ++rr) m += fu[d * R + rr] * fv[rr * D + f];
        mixs[tid] = m;
    }
    __syncthreads();
    const size_t idx = (size_t)bid * 256 + tid;
    const int dm = (int)(idx % DM_);
    const size_t bn = idx / DM_;
    const int d = dm / ds, s0 = dm % ds;
    const float* Ob = O + bn * DM_ + s0;
    float acc = 0.f;
    #pragma unroll
    for (int f = 0; f < D; ++f) acc += mixs[d * D + f] * Ob[(size_t)f * ds];
    const ush hh = f2bf(acc);
    Fh[idx] = hh; Fl[idx] = f2bf(acc - bf2f(hh));
}
__global__ __launch_bounds__(256) void k_mix(
        const float* __restrict__ logits,
        const float* __restrict__ fu0, const float* __restrict__ fv0,
        const float* __restrict__ fu1, const float* __restrict__ fv1,
        const float* __restrict__ fu2, const float* __restrict__ fv2,
        const float* __restrict__ fu3, const float* __restrict__ fv3,
        const float* __restrict__ O, ush* __restrict__ Fh, ush* __restrict__ Fl) {
    __shared__ float mixs[64];
    const int bid = blockIdx.x, tid = threadIdx.x;
    switch (sel_of(logits)) {
        case 0: mix_body<1>(bid, tid, fu0, fv0, O, Fh, Fl, mixs); break;
        case 1: mix_body<2>(bid, tid, fu1, fv1, O, Fh, Fl, mixs); break;
        case 2: mix_body<4>(bid, tid, fu2, fv2, O, Fh, Fl, mixs); break;
        case 3: mix_body<8>(bid, tid, fu3, fv3, O, Fh, Fl, mixs); break;
    }
}

// ---------------------------------------------------------------------------
// out = F @ wo — 32x64 tiles, grid 512 (round-13 version)
// ---------------------------------------------------------------------------
__global__ __launch_bounds__(256) void k_wo(
        const ush* __restrict__ Fh, const ush* __restrict__ Fl,
        const ush* __restrict__ wh, const ush* __restrict__ wl,
        float* __restrict__ out) {
    __shared__ ush lA[2][32 * 40];
    __shared__ ush lB[2][64 * 40];
    const int tid = threadIdx.x;
    const int bx = blockIdx.x & 15, by = blockIdx.x >> 4;
    const int row0 = by * 32, col0 = bx * 64;
    const int lane = tid & 63, w = tid >> 6;
    const int wq = w >> 1, wn = w & 1;
    const int lr = lane & 15, lb = lane >> 4;
    f32x4 acc[2] = {};

    for (int k0 = 0; k0 < DM_; k0 += 32) {
        {
            const int half = tid >> 7, t2 = tid & 127;
            const int srow = t2 >> 2, scg = t2 & 3;
            const ush* src = half ? Fl : Fh;
            *(bf16x8*)&lA[half][srow * 40 + scg * 8] =
                *(const bf16x8*)&src[(size_t)(row0 + srow) * DM_ + k0 + scg * 8];
        }
        {
            const int srow = tid >> 2, scg = tid & 3;
            *(bf16x8*)&lB[0][srow * 40 + scg * 8] =
                *(const bf16x8*)&wh[(size_t)(col0 + srow) * DM_ + k0 + scg * 8];
            *(bf16x8*)&lB[1][srow * 40 + scg * 8] =
                *(const bf16x8*)&wl[(size_t)(col0 + srow) * DM_ + k0 + scg * 8];
        }
        __syncthreads();
        const int ar = wq * 16 + lr;
        const bf16x8 ah = *(const bf16x8*)&lA[0][ar * 40 + lb * 8];
        const bf16x8 al = *(const bf16x8*)&lA[1][ar * 40 + lb * 8];
        #pragma unroll
        for (int ng = 0; ng < 2; ++ng) {
            const int br = wn * 32 + ng * 16 + lr;
            const bf16x8 bh = *(const bf16x8*)&lB[0][br * 40 + lb * 8];
            const bf16x8 bl = *(const bf16x8*)&lB[1][br * 40 + lb * 8];
            acc[ng] = mfma16(ah, bh, acc[ng]);
            acc[ng] = mfma16(al, bh, acc[ng]);
            acc[ng] = mfma16(ah, bl, acc[ng]);
        }
        __syncthreads();
    }
    #pragma unroll
    for (int ng = 0; ng < 2; ++ng)
        #pragma unroll
        for (int i = 0; i < 4; ++i) {
            const int r = row0 + wq * 16 + lb * 4 + i;
            const int c = col0 + wn * 32 + ng * 16 + lr;
            out[(size_t)r * DM_ + c] = acc[ng][i];
        }
}

// ---------------------------------------------------------------------------
extern "C" void kernel_launch(void* const* d_in, const int* in_sizes, int n_in,
                              void* d_out, int out_size, void* d_ws, size_t ws_size,
                              hipStream_t stream) {
    const float* x      = (const float*)d_in[0];
    const float* logits = (const float*)d_in[1];
    float* out = (float*)d_out;

    char* p = (char*)d_ws;
    p += 256;
    const size_t MB = 1024 * 1024;
    ush* Qh = (ush*)p; p += 2 * MB;
    ush* Ql = (ush*)p; p += 2 * MB;
    ush* Kh = (ush*)p; p += 2 * MB;
    ush* Kl = (ush*)p; p += 2 * MB;
    ush* Vth = (ush*)p; p += 4 * MB;           // padded V^T
    ush* Vtl = (ush*)p; p += 4 * MB;
    float* O = (float*)p; p += 4 * MB;
    ush* xh = (ush*)p; p += 2 * MB;
    ush* xl = (ush*)p; p += 2 * MB;
    ush* wqh = (ush*)p; p += 6 * MB;
    ush* wql = (ush*)p; p += 6 * MB;
    ush* woh = (ush*)p; p += 2 * MB;
    ush* wol = (ush*)p; p += 2 * MB;
    ush* Fh = xh, *Fl = xl;   // k_mix writes after k_qkv consumed xh/xl

    k_prep<<<dim3(3072), dim3(256), 0, stream>>>(
        logits, x,
        (const float*)d_in[2], (const float*)d_in[7],
        (const float*)d_in[12], (const float*)d_in[17],
        (const float*)d_in[3], (const float*)d_in[8],
        (const float*)d_in[13], (const float*)d_in[18],
        (const float*)d_in[4], (const float*)d_in[9],
        (const float*)d_in[14], (const float*)d_in[19],
        xh, xl, wqh, wql, woh, wol, Vth, Vtl);
    k_qkv<<<dim3(768), dim3(256), 0, stream>>>(logits, xh, xl, wqh, wql,
                                               Qh, Ql, Kh, Kl, Vth, Vtl);
    k_attn_1<<<dim3(256),  dim3(256), 0, stream>>>(logits, Qh, Ql, Kh, Kl, Vth, Vtl, O);
    k_attn_2<<<dim3(512),  dim3(256), 0, stream>>>(logits, Qh, Ql, Kh, Kl, Vth, Vtl, O);
    k_attn_4<<<dim3(1024), dim3(256), 0, stream>>>(logits, Qh, Ql, Kh, Kl, Vth, Vtl, O);
    k_attn_8<<<dim3(2048), dim3(256), 0, stream>>>(logits, Qh, Ql, Kh, Kl, Vth, Vtl, O);
    k_mix<<<dim3(B_ * N_ * DM_ / 256), dim3(256), 0, stream>>>(
        logits,
        (const float*)d_in[5],  (const float*)d_in[6],
        (const float*)d_in[10], (const float*)d_in[11],
        (const float*)d_in[15], (const float*)d_in[16],
        (const float*)d_in[20], (const float*)d_in[21],
        O, Fh, Fl);
    k_wo<<<dim3(512), dim3(256), 0, stream>>>(Fh, Fl, woh, wol, out);
}